// Round 16
// baseline (264.317 us; speedup 1.0000x reference)
//
#include <hip/hip_runtime.h>
#include <hip/hip_bf16.h>

// Problem constants
#define B_    32
#define T_    512
#define C_    384
#define D_    1536      // C*MULT
#define H_    1024
#define L_    255       // (T-SIZE)/STRIDE + 1
#define KP_   6144      // SIZE*D
#define ND_   16

// gemm1 (bf16, r3 engine): unchanged from r13/r15.
// gemm2 (MX-fp8 K=128): BM=128(l) BN=128(h), 512 thr = 8 waves (2Mx4N,
//   wave tile 64x32), 2 blocks/CU (16 waves/CU). A read DIRECT global->reg
//   (named union regs, k-linear order: addr = base + kt*128; wave touches
//   16 full 128B lines/instr). LDS holds only B: 2 x 16KB. Queue: A(u) 8
//   loads, then B(u+1) 2 gld_lds; vmcnt(10) retires B(u); vmcnt(2) retires
//   A(u); never 0 mid-loop.
#define BUFB 49152

using f32x4 = __attribute__((ext_vector_type(4))) float;
using s16x8 = __attribute__((ext_vector_type(8))) short;
using i32x4 = __attribute__((ext_vector_type(4))) int;
using i32x8 = __attribute__((ext_vector_type(8))) int;

__device__ __forceinline__ void gld_lds16(const void* g, void* l) {
    __builtin_amdgcn_global_load_lds(
        (const __attribute__((address_space(1))) void*)g,
        (__attribute__((address_space(3))) void*)l,
        16, 0, 0);
}

__device__ __forceinline__ f32x4 MFMA(s16x8 a, s16x8 b, f32x4 c) {
    return __builtin_amdgcn_mfma_f32_16x16x32_bf16(a, b, c, 0, 0, 0);
}

// MX-fp8 K=128: A scale 1.0 (e8m0 0x7F), B scale 2^-4 (0x7B; Wp pre-scaled x16)
__device__ __forceinline__ f32x4 MFMA8(i32x8 a, i32x8 b, f32x4 c) {
    return __builtin_amdgcn_mfma_scale_f32_16x16x128_f8f6f4(
        a, b, c, 0, 0, 0, 0x7F7F7F7F, 0, 0x7B7B7B7B);
}

// ------------- prep: conversions + mask/ts, one launch ------------------
__global__ __launch_bounds__(256) void prep(
    const float* __restrict__ sp, const float* __restrict__ we,
    const float* __restrict__ wp, const int* __restrict__ mIn,
    const int* __restrict__ tIn,
    __hip_bfloat16* __restrict__ spB, __hip_bfloat16* __restrict__ weB,
    unsigned char* __restrict__ wp8, float* __restrict__ out) {
    int id = blockIdx.x * 256 + threadIdx.x;
    if (id < 3932160) {
        const float* src; __hip_bfloat16* dst; int idx;
        if (id < 1572864) { src = sp; dst = spB; idx = id; }
        else              { src = we; dst = weB; idx = id - 1572864; }
        float4 v = reinterpret_cast<const float4*>(src)[idx];
        __hip_bfloat16 o[4] = {__float2bfloat16(v.x), __float2bfloat16(v.y),
                               __float2bfloat16(v.z), __float2bfloat16(v.w)};
        reinterpret_cast<ushort4*>(dst)[idx] = *reinterpret_cast<ushort4*>(o);
    } else if (id < 5505024) {
        int idx = id - 3932160;
        float4 v = reinterpret_cast<const float4*>(wp)[idx];
        int w = __builtin_amdgcn_cvt_pk_fp8_f32(v.x * 16.f, v.y * 16.f, 0, false);
        w = __builtin_amdgcn_cvt_pk_fp8_f32(v.z * 16.f, v.w * 16.f, w, true);
        reinterpret_cast<int*>(wp8)[idx] = w;
    } else {
        int i = id - 5505024;
        if (i < B_ * L_) {
            int b = i / L_, l = i % L_;
            const int* mb = mIn + b * T_ + 2 * l;
            int m = mb[0] * mb[1] * mb[2] * mb[3];
            const size_t offM = (size_t)B_ * L_ * H_;
            out[offM + i] = (float)m;
            out[offM + (size_t)B_ * L_ + i] = (float)tIn[b * T_ + l];
        }
    }
}

// ======================= gemm1 engine (r3/r9, bf16) ======================
__device__ __forceinline__ void tile_compute(const char* la, const char* lb,
                                             f32x4 (&acc)[4][4],
                                             int rA, int rB, int g) {
    const int sxA = rA & 7, sxB = rB & 7;
    s16x8 af0[4], bf0[4], af1[4], bf1[4];
    #pragma unroll
    for (int mi = 0; mi < 4; ++mi)
        af0[mi] = *(const s16x8*)(la + rA * 128 + mi * 2048 + ((g ^ sxA) << 4));
    #pragma unroll
    for (int ni = 0; ni < 4; ++ni)
        bf0[ni] = *(const s16x8*)(lb + rB * 128 + ni * 2048 + ((g ^ sxB) << 4));
    #pragma unroll
    for (int mi = 0; mi < 4; ++mi)
        af1[mi] = *(const s16x8*)(la + rA * 128 + mi * 2048 + (((4 + g) ^ sxA) << 4));
    #pragma unroll
    for (int ni = 0; ni < 4; ++ni)
        bf1[ni] = *(const s16x8*)(lb + rB * 128 + ni * 2048 + (((4 + g) ^ sxB) << 4));
    asm volatile("s_waitcnt lgkmcnt(8)" ::: "memory");
    __builtin_amdgcn_sched_barrier(0);
    __builtin_amdgcn_s_setprio(1);
    #pragma unroll
    for (int mi = 0; mi < 4; ++mi)
        #pragma unroll
        for (int ni = 0; ni < 4; ++ni)
            acc[mi][ni] = MFMA(af0[mi], bf0[ni], acc[mi][ni]);
    __builtin_amdgcn_s_setprio(0);
    asm volatile("s_waitcnt lgkmcnt(0)" ::: "memory");
    __builtin_amdgcn_sched_barrier(0);
    __builtin_amdgcn_s_setprio(1);
    #pragma unroll
    for (int mi = 0; mi < 4; ++mi)
        #pragma unroll
        for (int ni = 0; ni < 4; ++ni)
            acc[mi][ni] = MFMA(af1[mi], bf1[ni], acc[mi][ni]);
    __builtin_amdgcn_s_setprio(0);
}

__global__ __launch_bounds__(512, 2) void gemm1_embed(
    const __hip_bfloat16* __restrict__ Sp,
    const __hip_bfloat16* __restrict__ We,
    const float* __restrict__ bEmb,
    const int* __restrict__ dateIdx,
    unsigned char* __restrict__ X18) {
    extern __shared__ __align__(16) char lds[];
    const int tid  = threadIdx.x;
    const int lane = tid & 63, wid = tid >> 6;
    const int wr = wid >> 1, wc = wid & 1;
    const int id   = blockIdx.x;             // 0..767
    const int xcd  = id & 7, slot = id >> 3; // slot 0..95
    const int b    = xcd * 4 + slot / 24;
    const int tile = slot % 24;
    const int m0   = (tile % 2) * 256;
    const int n0   = (tile / 2) * 128;
    const int didx = dateIdx[b];
    const __hip_bfloat16* A  = Sp + (size_t)b * T_ * C_;
    const __hip_bfloat16* Bm = We + (size_t)didx * D_ * C_;
    const int KT = C_ / 64;              // 6

    auto stage = [&](int kt, int buf) {
        char* lA = lds + buf * BUFB;
        char* lB = lA + 32768;
        int k0 = kt * 64;
        #pragma unroll
        for (int i = 0; i < 4; ++i) {
            int p = i * 512 + tid;
            int row = p >> 3;
            int clog = (p & 7) ^ (row & 7);
            gld_lds16(A + (size_t)(m0 + row) * C_ + k0 + clog * 8,
                      lA + (i * 512 + wid * 64) * 16);
        }
        #pragma unroll
        for (int i = 0; i < 2; ++i) {
            int p = i * 512 + tid;
            int row = p >> 3;
            int clog = (p & 7) ^ (row & 7);
            gld_lds16(Bm + (size_t)(n0 + row) * C_ + k0 + clog * 8,
                      lB + (i * 512 + wid * 64) * 16);
        }
    };

    f32x4 acc[4][4] = {};
    const int rl = lane & 15, g = lane >> 4;
    const int rA = wr * 64 + rl, rB = wc * 64 + rl;

    stage(0, 0);
    stage(1, 1);
    for (int kt = 0; kt < KT - 2; ++kt) {
        stage(kt + 2, (kt + 2) % 3);
        asm volatile("s_waitcnt vmcnt(12)" ::: "memory");
        __builtin_amdgcn_s_barrier();
        const char* la = lds + (kt % 3) * BUFB;
        tile_compute(la, la + 32768, acc, rA, rB, g);
        __builtin_amdgcn_s_barrier();
    }
    asm volatile("s_waitcnt vmcnt(6)" ::: "memory");
    __builtin_amdgcn_s_barrier();
    {
        const char* la = lds + ((KT - 2) % 3) * BUFB;
        tile_compute(la, la + 32768, acc, rA, rB, g);
    }
    asm volatile("s_waitcnt vmcnt(0)" ::: "memory");
    __builtin_amdgcn_s_barrier();
    {
        const char* la = lds + ((KT - 1) % 3) * BUFB;
        tile_compute(la, la + 32768, acc, rA, rB, g);
    }

    // epilogue: + bias, exact gelu, * 32, store fp8 e4m3
    #pragma unroll
    for (int mi = 0; mi < 4; ++mi) {
        #pragma unroll
        for (int ni = 0; ni < 4; ++ni) {
            int col = n0 + wc * 64 + ni * 16 + rl;              // d
            float bg = bEmb[didx * D_ + col];
            #pragma unroll
            for (int r = 0; r < 4; ++r) {
                int row = m0 + wr * 64 + mi * 16 + g * 4 + r;   // t
                float v = acc[mi][ni][r] + bg;
                float gl = 0.5f * v * (1.0f + erff(v * 0.70710678118f)) * 32.0f;
                int pk = __builtin_amdgcn_cvt_pk_fp8_f32(gl, gl, 0, false);
                X18[((size_t)b * T_ + row) * D_ + col] = (unsigned char)pk;
            }
        }
    }
}

// ===== gemm2: MX-fp8 K128, A direct global->reg, B-only LDS, 16 w/CU =====
// grid 512: xcd=id&7; slot=id>>3; b=xcd*4+(slot>>4); t=slot&15:
// m0=(t&1)*128, n0=(t>>1)*128. 48 K128-tiles, K-LINEAR order
// (offset = kt*128 for both operands since (2l+s)*D + d = 2l*D + k).
__global__ __launch_bounds__(512, 4) void gemm2_proj(
    const unsigned char* __restrict__ X18,     // [B][T][D] fp8
    const unsigned char* __restrict__ Wp8,     // [H][KP] fp8 (x16 scaled)
    const float* __restrict__ bProj,
    const float* __restrict__ posTab,          // [MAXF][H] f32
    const int* __restrict__ tsIn,              // [B][T]
    float* __restrict__ outX) {                // [B][L][H]
    __shared__ __align__(16) char ldsB[2][16384];
    const int tid  = threadIdx.x;
    const int lane = tid & 63, wid = tid >> 6;     // 0..7
    const int wm = wid >> 2, wn = wid & 3;         // 2M x 4N
    const int id   = blockIdx.x;               // 0..511
    const int xcd  = id & 7, slot = id >> 3;   // 0..63
    const int b    = xcd * 4 + (slot >> 4);
    const int t    = slot & 15;
    const int m0   = (t & 1) * 128;            // l base
    const int n0   = (t >> 1) * 128;           // h base
    const unsigned char* Xb = X18 + (size_t)b * T_ * D_;
    const int KT = 48;                         // K128 tiles

    // ---- B staging (gload_lds, swizzled): 2 x 16B per thread per tile
    const unsigned char* bP0; const unsigned char* bP1;
    int dstC0, dstC1;
    {
        int p = tid, row = p >> 3, c = (p & 7) ^ (row & 7);
        bP0 = Wp8 + (size_t)(n0 + row) * KP_ + c * 16;
        dstC0 = (wid * 64) * 16;
        p = 512 + tid; row = p >> 3; c = (p & 7) ^ (row & 7);
        bP1 = Wp8 + (size_t)(n0 + row) * KP_ + c * 16;
        dstC1 = (512 + wid * 64) * 16;
    }

    // ---- A fragment global base addresses (k-linear: +kt*128 per tile)
    const int rl = lane & 15, g = lane >> 4, sx = rl & 7;
    const unsigned char* aA0; const unsigned char* aA1;
    const unsigned char* aA2; const unsigned char* aA3;
    {
        int l0 = m0 + wm * 64 + rl;
        int l1 = l0 + 16, l2 = l0 + 32, l3 = l0 + 48;
        if (l0 > 254) l0 = 254; if (l1 > 254) l1 = 254;
        if (l2 > 254) l2 = 254; if (l3 > 254) l3 = 254;
        aA0 = Xb + (size_t)(2 * l0) * D_ + g * 32;
        aA1 = Xb + (size_t)(2 * l1) * D_ + g * 32;
        aA2 = Xb + (size_t)(2 * l2) * D_ + g * 32;
        aA3 = Xb + (size_t)(2 * l3) * D_ + g * 32;
    }

    // ---- B fragment LDS geometry (2 x b128 per frag, XOR swizzled)
    const int ck0 = ((2 * g) ^ sx) << 4;
    const int ck1 = ((2 * g + 1) ^ sx) << 4;
    const int bOff0 = (wn * 32 + rl) * 128;
    const int bOff1 = (wn * 32 + 16 + rl) * 128;

    union U8 { i32x8 v; i32x4 h[2]; };
    f32x4 acc[4][2] = {};

    // prologue: stage B(0)
    gld_lds16(bP0, &ldsB[0][dstC0]);
    gld_lds16(bP1, &ldsB[0][dstC1]);

    for (int u = 0; u < KT; ++u) {
        int buf = u & 1;
        int ko = u * 128;
        // A(u) loads (8 x dwordx4, named regs)
        U8 A0, A1, A2, A3;
        A0.h[0] = *(const i32x4*)(aA0 + ko); A0.h[1] = *(const i32x4*)(aA0 + ko + 16);
        A1.h[0] = *(const i32x4*)(aA1 + ko); A1.h[1] = *(const i32x4*)(aA1 + ko + 16);
        A2.h[0] = *(const i32x4*)(aA2 + ko); A2.h[1] = *(const i32x4*)(aA2 + ko + 16);
        A3.h[0] = *(const i32x4*)(aA3 + ko); A3.h[1] = *(const i32x4*)(aA3 + ko + 16);
        __builtin_amdgcn_sched_barrier(0);
        // stage B(u+1) -> other buffer (2 gld_lds, newest in queue)
        if (u + 1 < KT) {
            gld_lds16(bP0 + ko + 128, &ldsB[buf ^ 1][dstC0]);
            gld_lds16(bP1 + ko + 128, &ldsB[buf ^ 1][dstC1]);
            __builtin_amdgcn_sched_barrier(0);
            asm volatile("s_waitcnt vmcnt(10)" ::: "memory");  // B(u) landed
        } else {
            asm volatile("s_waitcnt vmcnt(8)" ::: "memory");   // B(u) landed
        }
        __builtin_amdgcn_s_barrier();

        U8 Bv0, Bv1;
        Bv0.h[0] = *(const i32x4*)(&ldsB[buf][0] + bOff0 + ck0);
        Bv0.h[1] = *(const i32x4*)(&ldsB[buf][0] + bOff0 + ck1);
        Bv1.h[0] = *(const i32x4*)(&ldsB[buf][0] + bOff1 + ck0);
        Bv1.h[1] = *(const i32x4*)(&ldsB[buf][0] + bOff1 + ck1);
        if (u + 1 < KT) { asm volatile("s_waitcnt vmcnt(2) lgkmcnt(0)" ::: "memory"); }
        else            { asm volatile("s_waitcnt vmcnt(0) lgkmcnt(0)" ::: "memory"); }
        __builtin_amdgcn_sched_barrier(0);
        __builtin_amdgcn_s_setprio(1);
        acc[0][0] = MFMA8(A0.v, Bv0.v, acc[0][0]);
        acc[1][0] = MFMA8(A1.v, Bv0.v, acc[1][0]);
        acc[2][0] = MFMA8(A2.v, Bv0.v, acc[2][0]);
        acc[3][0] = MFMA8(A3.v, Bv0.v, acc[3][0]);
        acc[0][1] = MFMA8(A0.v, Bv1.v, acc[0][1]);
        acc[1][1] = MFMA8(A1.v, Bv1.v, acc[1][1]);
        acc[2][1] = MFMA8(A2.v, Bv1.v, acc[2][1]);
        acc[3][1] = MFMA8(A3.v, Bv1.v, acc[3][1]);
        __builtin_amdgcn_s_setprio(0);
        __builtin_amdgcn_s_barrier();    // all B reads of buf done
    }

    // epilogue: + b_proj + pos_table[ts[l]], fp32 store
    #pragma unroll
    for (int mi = 0; mi < 4; ++mi) {
        #pragma unroll
        for (int ni = 0; ni < 2; ++ni) {
            int h = n0 + wn * 32 + ni * 16 + rl;
            float bp = bProj[h];
            #pragma unroll
            for (int r = 0; r < 4; ++r) {
                int l = m0 + wm * 64 + mi * 16 + g * 4 + r;
                if (l < L_) {
                    int tsv = tsIn[b * T_ + l];
                    float v = acc[mi][ni][r] + bp + posTab[(size_t)tsv * H_ + h];
                    outX[((size_t)b * L_ + l) * H_ + h] = v;
                }
            }
        }
    }
}

extern "C" void kernel_launch(void* const* d_in, const int* in_sizes, int n_in,
                              void* d_out, int out_size, void* d_ws, size_t ws_size,
                              hipStream_t stream) {
    (void)in_sizes; (void)n_in; (void)out_size; (void)ws_size;
    const float* spikes  = (const float*)d_in[0];
    const int*   smask   = (const int*)d_in[1];
    const int*   sts     = (const int*)d_in[2];
    const int*   dateIdx = (const int*)d_in[3];
    const float* Wemb    = (const float*)d_in[4];
    const float* bEmb    = (const float*)d_in[5];
    const float* Wproj   = (const float*)d_in[6];
    const float* bProj   = (const float*)d_in[7];
    const float* posTab  = (const float*)d_in[8];
    float* out = (float*)d_out;

    // workspace layout (bytes):
    // X18 fp8   [B][T][D]  : 25165824   @ 0
    // SpB bf16  [B][T][C]  : 12582912   @ 25165824
    // WeB bf16  [ND][D][C] : 18874368   @ 37748736
    // Wp8 fp8   [H][KP]    : 6291456    @ 56623104
    char* ws = (char*)d_ws;
    unsigned char*  X18 = (unsigned char*)(ws);
    __hip_bfloat16* SpB = (__hip_bfloat16*)(ws + 25165824);
    __hip_bfloat16* WeB = (__hip_bfloat16*)(ws + 37748736);
    unsigned char*  Wp8 = (unsigned char*)(ws + 56623104);

    hipFuncSetAttribute((const void*)gemm1_embed,
                        hipFuncAttributeMaxDynamicSharedMemorySize, 3 * BUFB);

    prep<<<21536, 256, 0, stream>>>(spikes, Wemb, Wproj, smask, sts,
                                    SpB, WeB, Wp8, out);

    gemm1_embed<<<768, 512, 3 * BUFB, stream>>>(SpB, WeB, bEmb, dateIdx, X18);

    gemm2_proj<<<512, 512, 0, stream>>>(X18, Wp8, bProj, posTab, sts, out);
}

// Round 17
// 142.830 us; speedup vs baseline: 1.8506x; 1.8506x over previous
//
#include <hip/hip_runtime.h>
#include <hip/hip_bf16.h>

// Problem constants
#define B_    32
#define T_    512
#define C_    384
#define D_    1536      // C*MULT
#define H_    1024
#define L_    255       // (T-SIZE)/STRIDE + 1
#define KP_   6144      // SIZE*D
#define ND_   16

// gemm1 (bf16, r3 engine): unchanged from r13/r15.
// gemm2 (MX-fp8, 32x32x64 MFMA): block 128(l) x 256(h), BK=64, 8 waves
//   (2M x 4N) of 64x64 wave tiles (2x2 of 32x32 frags) -> LDS-read per FLOP
//   cut 3x vs r15. Tri-buffer 3 x 24KB = 72KB, 1 block/CU, grid 256
//   XCD batch-major. Stages are 3 gld_lds/thread; vmcnt(6) counted, never 0
//   mid-loop. LDS rows 64B, chunk swizzle c ^ ((row>>2)&3) (conflict-free
//   at BW floor). K-linear addressing: A addr = 2l*D + k, B = h*KP + k.
#define BUFB 49152
#define G2BUF 24576     // A 8KB + B 16KB

using f32x4  = __attribute__((ext_vector_type(4))) float;
using f32x16 = __attribute__((ext_vector_type(16))) float;
using s16x8  = __attribute__((ext_vector_type(8))) short;
using i32x4  = __attribute__((ext_vector_type(4))) int;
using i32x8  = __attribute__((ext_vector_type(8))) int;

__device__ __forceinline__ void gld_lds16(const void* g, void* l) {
    __builtin_amdgcn_global_load_lds(
        (const __attribute__((address_space(1))) void*)g,
        (__attribute__((address_space(3))) void*)l,
        16, 0, 0);
}

__device__ __forceinline__ f32x4 MFMA(s16x8 a, s16x8 b, f32x4 c) {
    return __builtin_amdgcn_mfma_f32_16x16x32_bf16(a, b, c, 0, 0, 0);
}

// MX-fp8 32x32x64: A scale 1.0 (0x7F), B scale 2^-4 (0x7B; Wp pre-scaled x16)
__device__ __forceinline__ f32x16 MFMA8W(i32x8 a, i32x8 b, f32x16 c) {
    return __builtin_amdgcn_mfma_scale_f32_32x32x64_f8f6f4(
        a, b, c, 0, 0, 0, 0x7F7F7F7F, 0, 0x7B7B7B7B);
}

// ------------- prep: conversions + mask/ts, one launch ------------------
__global__ __launch_bounds__(256) void prep(
    const float* __restrict__ sp, const float* __restrict__ we,
    const float* __restrict__ wp, const int* __restrict__ mIn,
    const int* __restrict__ tIn,
    __hip_bfloat16* __restrict__ spB, __hip_bfloat16* __restrict__ weB,
    unsigned char* __restrict__ wp8, float* __restrict__ out) {
    int id = blockIdx.x * 256 + threadIdx.x;
    if (id < 3932160) {
        const float* src; __hip_bfloat16* dst; int idx;
        if (id < 1572864) { src = sp; dst = spB; idx = id; }
        else              { src = we; dst = weB; idx = id - 1572864; }
        float4 v = reinterpret_cast<const float4*>(src)[idx];
        __hip_bfloat16 o[4] = {__float2bfloat16(v.x), __float2bfloat16(v.y),
                               __float2bfloat16(v.z), __float2bfloat16(v.w)};
        reinterpret_cast<ushort4*>(dst)[idx] = *reinterpret_cast<ushort4*>(o);
    } else if (id < 5505024) {
        int idx = id - 3932160;
        float4 v = reinterpret_cast<const float4*>(wp)[idx];
        int w = __builtin_amdgcn_cvt_pk_fp8_f32(v.x * 16.f, v.y * 16.f, 0, false);
        w = __builtin_amdgcn_cvt_pk_fp8_f32(v.z * 16.f, v.w * 16.f, w, true);
        reinterpret_cast<int*>(wp8)[idx] = w;
    } else {
        int i = id - 5505024;
        if (i < B_ * L_) {
            int b = i / L_, l = i % L_;
            const int* mb = mIn + b * T_ + 2 * l;
            int m = mb[0] * mb[1] * mb[2] * mb[3];
            const size_t offM = (size_t)B_ * L_ * H_;
            out[offM + i] = (float)m;
            out[offM + (size_t)B_ * L_ + i] = (float)tIn[b * T_ + l];
        }
    }
}

// ======================= gemm1 engine (r3/r9, bf16) ======================
__device__ __forceinline__ void tile_compute(const char* la, const char* lb,
                                             f32x4 (&acc)[4][4],
                                             int rA, int rB, int g) {
    const int sxA = rA & 7, sxB = rB & 7;
    s16x8 af0[4], bf0[4], af1[4], bf1[4];
    #pragma unroll
    for (int mi = 0; mi < 4; ++mi)
        af0[mi] = *(const s16x8*)(la + rA * 128 + mi * 2048 + ((g ^ sxA) << 4));
    #pragma unroll
    for (int ni = 0; ni < 4; ++ni)
        bf0[ni] = *(const s16x8*)(lb + rB * 128 + ni * 2048 + ((g ^ sxB) << 4));
    #pragma unroll
    for (int mi = 0; mi < 4; ++mi)
        af1[mi] = *(const s16x8*)(la + rA * 128 + mi * 2048 + (((4 + g) ^ sxA) << 4));
    #pragma unroll
    for (int ni = 0; ni < 4; ++ni)
        bf1[ni] = *(const s16x8*)(lb + rB * 128 + ni * 2048 + (((4 + g) ^ sxB) << 4));
    asm volatile("s_waitcnt lgkmcnt(8)" ::: "memory");
    __builtin_amdgcn_sched_barrier(0);
    __builtin_amdgcn_s_setprio(1);
    #pragma unroll
    for (int mi = 0; mi < 4; ++mi)
        #pragma unroll
        for (int ni = 0; ni < 4; ++ni)
            acc[mi][ni] = MFMA(af0[mi], bf0[ni], acc[mi][ni]);
    __builtin_amdgcn_s_setprio(0);
    asm volatile("s_waitcnt lgkmcnt(0)" ::: "memory");
    __builtin_amdgcn_sched_barrier(0);
    __builtin_amdgcn_s_setprio(1);
    #pragma unroll
    for (int mi = 0; mi < 4; ++mi)
        #pragma unroll
        for (int ni = 0; ni < 4; ++ni)
            acc[mi][ni] = MFMA(af1[mi], bf1[ni], acc[mi][ni]);
    __builtin_amdgcn_s_setprio(0);
}

__global__ __launch_bounds__(512, 2) void gemm1_embed(
    const __hip_bfloat16* __restrict__ Sp,
    const __hip_bfloat16* __restrict__ We,
    const float* __restrict__ bEmb,
    const int* __restrict__ dateIdx,
    unsigned char* __restrict__ X18) {
    extern __shared__ __align__(16) char lds[];
    const int tid  = threadIdx.x;
    const int lane = tid & 63, wid = tid >> 6;
    const int wr = wid >> 1, wc = wid & 1;
    const int id   = blockIdx.x;             // 0..767
    const int xcd  = id & 7, slot = id >> 3; // slot 0..95
    const int b    = xcd * 4 + slot / 24;
    const int tile = slot % 24;
    const int m0   = (tile % 2) * 256;
    const int n0   = (tile / 2) * 128;
    const int didx = dateIdx[b];
    const __hip_bfloat16* A  = Sp + (size_t)b * T_ * C_;
    const __hip_bfloat16* Bm = We + (size_t)didx * D_ * C_;
    const int KT = C_ / 64;              // 6

    auto stage = [&](int kt, int buf) {
        char* lA = lds + buf * BUFB;
        char* lB = lA + 32768;
        int k0 = kt * 64;
        #pragma unroll
        for (int i = 0; i < 4; ++i) {
            int p = i * 512 + tid;
            int row = p >> 3;
            int clog = (p & 7) ^ (row & 7);
            gld_lds16(A + (size_t)(m0 + row) * C_ + k0 + clog * 8,
                      lA + (i * 512 + wid * 64) * 16);
        }
        #pragma unroll
        for (int i = 0; i < 2; ++i) {
            int p = i * 512 + tid;
            int row = p >> 3;
            int clog = (p & 7) ^ (row & 7);
            gld_lds16(Bm + (size_t)(n0 + row) * C_ + k0 + clog * 8,
                      lB + (i * 512 + wid * 64) * 16);
        }
    };

    f32x4 acc[4][4] = {};
    const int rl = lane & 15, g = lane >> 4;
    const int rA = wr * 64 + rl, rB = wc * 64 + rl;

    stage(0, 0);
    stage(1, 1);
    for (int kt = 0; kt < KT - 2; ++kt) {
        stage(kt + 2, (kt + 2) % 3);
        asm volatile("s_waitcnt vmcnt(12)" ::: "memory");
        __builtin_amdgcn_s_barrier();
        const char* la = lds + (kt % 3) * BUFB;
        tile_compute(la, la + 32768, acc, rA, rB, g);
        __builtin_amdgcn_s_barrier();
    }
    asm volatile("s_waitcnt vmcnt(6)" ::: "memory");
    __builtin_amdgcn_s_barrier();
    {
        const char* la = lds + ((KT - 2) % 3) * BUFB;
        tile_compute(la, la + 32768, acc, rA, rB, g);
    }
    asm volatile("s_waitcnt vmcnt(0)" ::: "memory");
    __builtin_amdgcn_s_barrier();
    {
        const char* la = lds + ((KT - 1) % 3) * BUFB;
        tile_compute(la, la + 32768, acc, rA, rB, g);
    }

    // epilogue: + bias, exact gelu, * 32, store fp8 e4m3
    #pragma unroll
    for (int mi = 0; mi < 4; ++mi) {
        #pragma unroll
        for (int ni = 0; ni < 4; ++ni) {
            int col = n0 + wc * 64 + ni * 16 + rl;              // d
            float bg = bEmb[didx * D_ + col];
            #pragma unroll
            for (int r = 0; r < 4; ++r) {
                int row = m0 + wr * 64 + mi * 16 + g * 4 + r;   // t
                float v = acc[mi][ni][r] + bg;
                float gl = 0.5f * v * (1.0f + erff(v * 0.70710678118f)) * 32.0f;
                int pk = __builtin_amdgcn_cvt_pk_fp8_f32(gl, gl, 0, false);
                X18[((size_t)b * T_ + row) * D_ + col] = (unsigned char)pk;
            }
        }
    }
}

// ===== gemm2: MX-fp8 32x32x64, 128x256 block, 8 waves of 64x64 ===========
// grid 256: xcd=id&7; slot=id>>3 (0..31); b=xcd*4+(slot>>3); t=slot&7:
// m0=(t&1)*128, n0=(t>>1)*256. 96 K64-tiles, k-linear addressing.
__global__ __launch_bounds__(512, 2) void gemm2_proj(
    const unsigned char* __restrict__ X18,     // [B][T][D] fp8
    const unsigned char* __restrict__ Wp8,     // [H][KP] fp8 (x16 scaled)
    const float* __restrict__ bProj,
    const float* __restrict__ posTab,          // [MAXF][H] f32
    const int* __restrict__ tsIn,              // [B][T]
    float* __restrict__ outX) {                // [B][L][H]
    extern __shared__ __align__(16) char lds2[];   // 3 x 24KB [A 8K | B 16K]
    const int tid  = threadIdx.x;
    const int lane = tid & 63, wid = tid >> 6;     // 0..7
    const int wm = wid >> 2, wn = wid & 3;         // 2M x 4N, wave tile 64x64
    const int id   = blockIdx.x;               // 0..255
    const int xcd  = id & 7, slot = id >> 3;   // 0..31
    const int b    = xcd * 4 + (slot >> 3);
    const int t    = slot & 7;
    const int m0   = (t & 1) * 128;            // l base
    const int n0   = (t >> 1) * 256;           // h base
    const unsigned char* Xb = X18 + (size_t)b * T_ * D_;
    const int KT = 96;                         // K64 tiles

    // ---- staging sources (3 gld_lds/thread/tile; k-linear +64/tile)
    // A: 512 chunks [row 0..127][c_phys 0..3], c_log = c_phys ^ ((row>>2)&3)
    const unsigned char* aSrc;
    {
        int row = tid >> 2;
        int cl = (tid & 3) ^ ((row >> 2) & 3);
        int l = m0 + row; if (l > 254) l = 254;
        aSrc = Xb + (size_t)(2 * l) * D_ + cl * 16;
    }
    // B: 1024 chunks [row 0..255][c 0..3], two per thread
    const unsigned char* bSrc0; const unsigned char* bSrc1;
    {
        int p = tid, row = p >> 2, cl = (p & 3) ^ ((row >> 2) & 3);
        bSrc0 = Wp8 + (size_t)(n0 + row) * KP_ + cl * 16;
        p = 512 + tid; row = p >> 2; cl = (p & 3) ^ ((row >> 2) & 3);
        bSrc1 = Wp8 + (size_t)(n0 + row) * KP_ + cl * 16;
    }
    auto stage = [&](int kt, int buf) {
        int ko = kt * 64;
        char* base = lds2 + buf * G2BUF;
        gld_lds16(aSrc + ko, base + tid * 16);                    // A chunk tid
        gld_lds16(bSrc0 + ko, base + 8192 + tid * 16);            // B chunk tid
        gld_lds16(bSrc1 + ko, base + 8192 + (512 + tid) * 16);    // B chunk 512+tid
    };

    // ---- fragment read offsets (tile-invariant):
    // A frag(mi): row = wm*64 + mi*32 + (lane&31); lane k-chunks
    // c_log = (lane>>5)*2 + j; addr = row*64 + (c_log^((row>>2)&3))*16.
    const int l31 = lane & 31, kg = lane >> 5;
    int aOff[2][2], bOff[2][2];
    #pragma unroll
    for (int mi = 0; mi < 2; ++mi) {
        int row = wm * 64 + mi * 32 + l31;
        int sw = (row >> 2) & 3;
        aOff[mi][0] = row * 64 + (((kg * 2) ^ sw) << 4);
        aOff[mi][1] = row * 64 + (((kg * 2 + 1) ^ sw) << 4);
    }
    #pragma unroll
    for (int ni = 0; ni < 2; ++ni) {
        int row = wn * 64 + ni * 32 + l31;
        int sw = (row >> 2) & 3;
        bOff[ni][0] = 8192 + row * 64 + (((kg * 2) ^ sw) << 4);
        bOff[ni][1] = 8192 + row * 64 + (((kg * 2 + 1) ^ sw) << 4);
    }

    union U8 { i32x8 v; i32x4 h[2]; };
    f32x16 acc[2][2] = {};

    stage(0, 0);
    stage(1, 1);
    for (int u = 0; u < KT; ++u) {
        if (u + 2 < KT) {
            stage(u + 2, (u + 2) % 3);
            asm volatile("s_waitcnt vmcnt(6)" ::: "memory");
        } else if (u + 1 < KT) {
            asm volatile("s_waitcnt vmcnt(3)" ::: "memory");
        } else {
            asm volatile("s_waitcnt vmcnt(0)" ::: "memory");
        }
        __builtin_amdgcn_s_barrier();

        const char* base = lds2 + (u % 3) * G2BUF;
        U8 A0, A1, B0, B1;
        A0.h[0] = *(const i32x4*)(base + aOff[0][0]);
        A0.h[1] = *(const i32x4*)(base + aOff[0][1]);
        B0.h[0] = *(const i32x4*)(base + bOff[0][0]);
        B0.h[1] = *(const i32x4*)(base + bOff[0][1]);
        A1.h[0] = *(const i32x4*)(base + aOff[1][0]);
        A1.h[1] = *(const i32x4*)(base + aOff[1][1]);
        B1.h[0] = *(const i32x4*)(base + bOff[1][0]);
        B1.h[1] = *(const i32x4*)(base + bOff[1][1]);
        asm volatile("s_waitcnt lgkmcnt(4)" ::: "memory");
        __builtin_amdgcn_sched_barrier(0);
        __builtin_amdgcn_s_setprio(1);
        acc[0][0] = MFMA8W(A0.v, B0.v, acc[0][0]);
        __builtin_amdgcn_s_setprio(0);
        asm volatile("s_waitcnt lgkmcnt(2)" ::: "memory");
        __builtin_amdgcn_sched_barrier(0);
        __builtin_amdgcn_s_setprio(1);
        acc[1][0] = MFMA8W(A1.v, B0.v, acc[1][0]);
        __builtin_amdgcn_s_setprio(0);
        asm volatile("s_waitcnt lgkmcnt(0)" ::: "memory");
        __builtin_amdgcn_sched_barrier(0);
        __builtin_amdgcn_s_setprio(1);
        acc[0][1] = MFMA8W(A0.v, B1.v, acc[0][1]);
        acc[1][1] = MFMA8W(A1.v, B1.v, acc[1][1]);
        __builtin_amdgcn_s_setprio(0);
        __builtin_amdgcn_s_barrier();
    }

    // epilogue: + b_proj + pos_table[ts[l]], fp32 store.
    // 32x32 C/D layout: col = lane&31, row = (r&3) + 8*(r>>2) + 4*(lane>>5)
    #pragma unroll
    for (int mi = 0; mi < 2; ++mi) {
        #pragma unroll
        for (int ni = 0; ni < 2; ++ni) {
            int h = n0 + wn * 64 + ni * 32 + l31;
            float bp = bProj[h];
            #pragma unroll
            for (int r = 0; r < 16; ++r) {
                int row = (r & 3) + 8 * (r >> 2) + 4 * kg;
                int l = m0 + wm * 64 + mi * 32 + row;
                if (l < L_) {
                    int tsv = tsIn[b * T_ + l];
                    float v = acc[mi][ni][r] + bp + posTab[(size_t)tsv * H_ + h];
                    outX[((size_t)b * L_ + l) * H_ + h] = v;
                }
            }
        }
    }
}

extern "C" void kernel_launch(void* const* d_in, const int* in_sizes, int n_in,
                              void* d_out, int out_size, void* d_ws, size_t ws_size,
                              hipStream_t stream) {
    (void)in_sizes; (void)n_in; (void)out_size; (void)ws_size;
    const float* spikes  = (const float*)d_in[0];
    const int*   smask   = (const int*)d_in[1];
    const int*   sts     = (const int*)d_in[2];
    const int*   dateIdx = (const int*)d_in[3];
    const float* Wemb    = (const float*)d_in[4];
    const float* bEmb    = (const float*)d_in[5];
    const float* Wproj   = (const float*)d_in[6];
    const float* bProj   = (const float*)d_in[7];
    const float* posTab  = (const float*)d_in[8];
    float* out = (float*)d_out;

    // workspace layout (bytes):
    // X18 fp8   [B][T][D]  : 25165824   @ 0
    // SpB bf16  [B][T][C]  : 12582912   @ 25165824
    // WeB bf16  [ND][D][C] : 18874368   @ 37748736
    // Wp8 fp8   [H][KP]    : 6291456    @ 56623104
    char* ws = (char*)d_ws;
    unsigned char*  X18 = (unsigned char*)(ws);
    __hip_bfloat16* SpB = (__hip_bfloat16*)(ws + 25165824);
    __hip_bfloat16* WeB = (__hip_bfloat16*)(ws + 37748736);
    unsigned char*  Wp8 = (unsigned char*)(ws + 56623104);

    hipFuncSetAttribute((const void*)gemm1_embed,
                        hipFuncAttributeMaxDynamicSharedMemorySize, 3 * BUFB);
    hipFuncSetAttribute((const void*)gemm2_proj,
                        hipFuncAttributeMaxDynamicSharedMemorySize, 3 * G2BUF);

    prep<<<21536, 256, 0, stream>>>(spikes, Wemb, Wproj, smask, sts,
                                    SpB, WeB, Wp8, out);

    gemm1_embed<<<768, 512, 3 * BUFB, stream>>>(SpB, WeB, bEmb, dateIdx, X18);

    gemm2_proj<<<256, 512, 3 * G2BUF, stream>>>(X18, Wp8, bProj, posTab, sts, out);
}